// Round 8
// baseline (267.167 us; speedup 1.0000x reference)
//
#include <hip/hip_runtime.h>
#include <hip/hip_bf16.h>

typedef __attribute__((ext_vector_type(8))) short short8;
typedef __attribute__((ext_vector_type(4))) float floatx4;

#define B_SZ   32
#define L_IN   8192
#define C_INCH 64
#define KW     3
#define F_OUT  128
#define L_OUT  (L_IN - KW + 1)   // 8190
#define KDIM   (KW * C_INCH)     // 192

#define TILE_L  64
#define NGRID   (B_SZ * (L_IN / TILE_L))   // 4096 blocks (proven best grid, occ 4)

// W fragment table: 8 n-tiles x 6 k-steps x 64 lanes, one short8 (16B) each.
#define WTAB_ELEMS (8 * 6 * 64)  // 3072 -> 49152 bytes

// packed fp32x2 -> bf16x2 (RNE, emits v_cvt_pk_bf16_f32)
__device__ __forceinline__ unsigned pk2(float a, float b) {
    __hip_bfloat162 h = __float22bfloat162_rn(make_float2(a, b));
    unsigned u;
    __builtin_memcpy(&u, &h, 4);
    return u;
}

// R7 prep: pre-swizzle w (fp32 [192][128]) into bf16 MFMA fragment layout.
// wtab[(nt*6 + s)*64 + lane] holds W[k = s*32 + q*8 + j][f = nt*16 + nl].
__global__ __launch_bounds__(256) void w_prep(const float* __restrict__ w,
                                              short8* __restrict__ wtab) {
    int id = blockIdx.x * 256 + threadIdx.x;
    if (id >= WTAB_ELEMS) return;
    int lane = id & 63;
    int s    = (id >> 6) % 6;
    int nt   = id / 384;
    int nl = lane & 15, q = lane >> 4;
    const float* __restrict__ wf = w + nt * 16 + nl;
    float t[8];
#pragma unroll
    for (int j = 0; j < 8; ++j) t[j] = wf[(s * 32 + q * 8 + j) * F_OUT];
    union { unsigned u[4]; short8 v; } hb;
    hb.u[0] = pk2(t[0], t[1]);
    hb.u[1] = pk2(t[2], t[3]);
    hb.u[2] = pk2(t[4], t[5]);
    hb.u[3] = pk2(t[6], t[7]);
    wtab[id] = hb.v;
}

// R13: BARRIER-FREE direct-load kernel.
// R12 POST-MORTEM: DMA staging == register staging (~61us) -> the staging
// chain was never the bottleneck. Every variant so far shares the real
// bottleneck: barrier-phased blocks (load phase -> syncthreads vmcnt(0)
// drain -> compute -> store drain) phase-align the 4 resident blocks, so
// the read pipe idles during compute/store. conv runs at 2.4 TB/s (38% of
// achievable) with ALL pipes <10% busy.
// Fix (lesson #7: don't stage what the cache catches): x's only reuse is
// 4 waves of one block reading the same 17KB tile -> L1/L2 catch it. Each
// lane's A-fragment is 8 CONTIGUOUS fp32 in x (k = sh*64+sl*32+q*8+j ->
// row l+sh, ch = sl*32+q*8+j), so with one base pointer per m-tile all 48
// loads/wave are global_load_dwordx4 with immediate offsets (<= 656B).
// kloop = 48 dwordx4 + 96 cvt_pk + 48 MFMA; ZERO LDS, ZERO barriers.
// Waves free-run: one wave's loads overlap other waves' MFMA/stores
// continuously, blocks retire/backfill without cohort alignment.
// OOB rows clamp to the last valid row-2 (only feeds non-stored outputs).
template <bool PREP>
__global__ __launch_bounds__(256, 4) void conv1d_mfma(const float* __restrict__ x,
                                                      const float* __restrict__ w,
                                                      const float* __restrict__ bias,
                                                      float* __restrict__ out,
                                                      const short8* __restrict__ wtab) {
    const int tid  = threadIdx.x;
    const int lane = tid & 63;
    const int wave = tid >> 6;
    const int q    = lane >> 4;   // quad 0..3
    const int nl   = lane & 15;

    const int g  = blockIdx.x;
    const int b  = g >> 7;              // 128 tiles per batch row
    const int l0 = (g & 127) * TILE_L;

    // ---- B fragments: 12 coalesced 16B loads from the prepped table ----
    short8 bfrag[6][2];
    if (PREP) {
#pragma unroll
        for (int n = 0; n < 2; ++n)
#pragma unroll
            for (int s = 0; s < 6; ++s)
                bfrag[s][n] = wtab[(((wave * 2 + n) * 6 + s) << 6) + lane];
    } else {
        // fallback (workspace too small): build in-kernel
#pragma unroll
        for (int n = 0; n < 2; ++n) {
            const int f = (wave * 2 + n) * 16 + nl;
            const float* __restrict__ wf = w + f;
#pragma unroll
            for (int s = 0; s < 6; ++s) {
                float t[8];
#pragma unroll
                for (int j = 0; j < 8; ++j)
                    t[j] = wf[(s * 32 + q * 8 + j) * F_OUT];
                union { unsigned u[4]; short8 v; } hb;
                hb.u[0] = pk2(t[0], t[1]);
                hb.u[1] = pk2(t[2], t[3]);
                hb.u[2] = pk2(t[4], t[5]);
                hb.u[3] = pk2(t[6], t[7]);
                bfrag[s][n] = hb.v;
            }
        }
    }

    // bias: swapped C/D layout -> lane holds f = base + q*4 + r -> float4
    float4 bv[2];
#pragma unroll
    for (int n = 0; n < 2; ++n)
        bv[n] = *(const float4*)(bias + (wave * 2 + n) * 16 + q * 4);

    // ---- per-m A base pointers: row l0+m*16+nl, ch q*8. All 6 k-step loads
    //      off each base are immediate offsets (sh*256 + sl*128 + {0,16} B).
    //      Clamp so row+2 stays in-buffer; clamped lanes only feed l>=L_OUT.
    const float* abase[4];
#pragma unroll
    for (int m = 0; m < 4; ++m) {
        int grow = b * L_IN + l0 + m * 16 + nl;
        grow = grow < (B_SZ * L_IN - 3) ? grow : (B_SZ * L_IN - 3);
        abase[m] = x + (size_t)grow * C_INCH + q * 8;
    }

    // ---- K-loop: 6 steps of 32; 4 m x 2 n per wave (swapped operands) ----
    floatx4 acc[4][2];
#pragma unroll
    for (int m = 0; m < 4; ++m)
#pragma unroll
        for (int n = 0; n < 2; ++n) acc[m][n] = (floatx4){0.f, 0.f, 0.f, 0.f};

#pragma unroll
    for (int s = 0; s < 6; ++s) {
        const int foff = (s >> 1) * C_INCH + (s & 1) * 32;  // compile-time
#pragma unroll
        for (int m = 0; m < 4; ++m) {
            const float* p = abase[m] + foff;
            floatx4 c0 = *(const floatx4*)(p);
            floatx4 c1 = *(const floatx4*)(p + 4);
            union { unsigned u[4]; short8 v; } h;
            h.u[0] = pk2(c0[0], c0[1]);
            h.u[1] = pk2(c0[2], c0[3]);
            h.u[2] = pk2(c1[0], c1[1]);
            h.u[3] = pk2(c1[2], c1[3]);
#pragma unroll
            for (int n = 0; n < 2; ++n)
                acc[m][n] = __builtin_amdgcn_mfma_f32_16x16x32_bf16(
                    bfrag[s][n], h.v, acc[m][n], 0, 0, 0);
        }
    }

    // ---- epilogue: lane(nl,q) holds f = base+q*4+r (r=0..3), l = l0+m*16+nl
    //      -> one float4 store per (m,n) ----
#pragma unroll
    for (int n = 0; n < 2; ++n) {
        const int fb = (wave * 2 + n) * 16 + q * 4;
#pragma unroll
        for (int m = 0; m < 4; ++m) {
            const int l = l0 + m * 16 + nl;
            if (l < L_OUT) {
                float4 v;
                v.x = acc[m][n][0] + bv[n].x;
                v.y = acc[m][n][1] + bv[n].y;
                v.z = acc[m][n][2] + bv[n].z;
                v.w = acc[m][n][3] + bv[n].w;
                v.x = v.x > 0.f ? v.x : 0.f;
                v.y = v.y > 0.f ? v.y : 0.f;
                v.z = v.z > 0.f ? v.z : 0.f;
                v.w = v.w > 0.f ? v.w : 0.f;
                *(float4*)(out + ((size_t)b * L_OUT + l) * F_OUT + fb) = v;
            }
        }
    }
}

extern "C" void kernel_launch(void* const* d_in, const int* in_sizes, int n_in,
                              void* d_out, int out_size, void* d_ws, size_t ws_size,
                              hipStream_t stream) {
    const float* x    = (const float*)d_in[0];
    const float* w    = (const float*)d_in[1];
    const float* bias = (const float*)d_in[2];
    float* out        = (float*)d_out;

    if (d_ws != nullptr && ws_size >= (size_t)WTAB_ELEMS * sizeof(short8)) {
        short8* wtab = (short8*)d_ws;
        w_prep<<<dim3((WTAB_ELEMS + 255) / 256), 256, 0, stream>>>(w, wtab);
        conv1d_mfma<true><<<dim3(NGRID), 256, 0, stream>>>(x, w, bias, out, wtab);
    } else {
        conv1d_mfma<false><<<dim3(NGRID), 256, 0, stream>>>(x, w, bias, out, nullptr);
    }
}

// Round 9
// 192.770 us; speedup vs baseline: 1.3859x; 1.3859x over previous
//
#include <hip/hip_runtime.h>
#include <hip/hip_bf16.h>

typedef __attribute__((ext_vector_type(8))) short short8;
typedef __attribute__((ext_vector_type(4))) float floatx4;

#define B_SZ   32
#define L_IN   8192
#define C_INCH 64
#define KW     3
#define F_OUT  128
#define L_OUT  (L_IN - KW + 1)   // 8190
#define KDIM   (KW * C_INCH)     // 192

#define TILE_L  64
#define AROWS   (TILE_L + 2)     // 66
#define TPB     2                // double-buffered DMA pipeline
#define NGRID   (B_SZ * (L_IN / TILE_L) / TPB)   // 2048 blocks

// W fragment table: 8 n-tiles x 6 k-steps x 64 lanes, one short8 (16B) each.
#define WTAB_ELEMS (8 * 6 * 64)  // 3072 -> 49152 bytes

// packed fp32x2 -> bf16x2 (RNE, emits v_cvt_pk_bf16_f32)
__device__ __forceinline__ unsigned pk2(float a, float b) {
    __hip_bfloat162 h = __float22bfloat162_rn(make_float2(a, b));
    unsigned u;
    __builtin_memcpy(&u, &h, 4);
    return u;
}

// R7 prep: pre-swizzle w (fp32 [192][128]) into bf16 MFMA fragment layout.
// wtab[(nt*6 + s)*64 + lane] holds W[k = s*32 + q*8 + j][f = nt*16 + nl].
__global__ __launch_bounds__(256) void w_prep(const float* __restrict__ w,
                                              short8* __restrict__ wtab) {
    int id = blockIdx.x * 256 + threadIdx.x;
    if (id >= WTAB_ELEMS) return;
    int lane = id & 63;
    int s    = (id >> 6) % 6;
    int nt   = id / 384;
    int nl = lane & 15, q = lane >> 4;
    const float* __restrict__ wf = w + nt * 16 + nl;
    float t[8];
#pragma unroll
    for (int j = 0; j < 8; ++j) t[j] = wf[(s * 32 + q * 8 + j) * F_OUT];
    union { unsigned u[4]; short8 v; } hb;
    hb.u[0] = pk2(t[0], t[1]);
    hb.u[1] = pk2(t[2], t[3]);
    hb.u[2] = pk2(t[4], t[5]);
    hb.u[3] = pk2(t[6], t[7]);
    wtab[id] = hb.v;
}

// R14: R12's proven DMA staging (zero staging regs, source-XOR swizzle,
// in-kloop fp32->bf16 cvt) + TPB=2 DOUBLE-BUFFERED pipeline with counted
// vmcnt — the overlap reg-based TPB couldn't afford at occ 4 (R8b spilled)
// and DMA gets for free.
// R13 POST-MORTEM: direct global loads (no LDS) collapsed to VGPR=36 (the
// compiler dropped bfrag and re-loads W in-loop) + scattered 16B lane
// addresses -> 137us. LDS staging is for COALESCING SHAPE, not reuse.
// vmcnt bookkeeping (uniform per wave): stage = 4 unconditional wave-wide
// DMAs (rows 0-63) + 1 half-exec halo DMA (lane<32, rows 64-65, issued by
// EVERY wave -> identical counts; duplicate same-data LDS writes benign).
// Sequence: stage(b0) stage(b1) vmcnt(5) bar | kloop0 stores0 vmcnt(8) bar |
// kloop1 stores1. buf1's DMA flies under kloop0+stores0; vmcnt never 0.
template <bool PREP>
__global__ __launch_bounds__(256, 4) void conv1d_mfma(const float* __restrict__ x,
                                                      const float* __restrict__ w,
                                                      const float* __restrict__ bias,
                                                      float* __restrict__ out,
                                                      const short8* __restrict__ wtab) {
    __shared__ __align__(16) float a_raw[2][AROWS * C_INCH];  // 2 x 16896 B

    const int tid  = threadIdx.x;
    const int lane = tid & 63;
    const int wave = tid >> 6;
    const int q    = lane >> 4;   // quad 0..3
    const int nl   = lane & 15;

    const int g      = blockIdx.x;
    const int b      = g >> 6;                     // 64 tile-pairs per batch row
    const int l_base = (g & 63) * (TPB * TILE_L);  // 128-row span per block

    // ---- B fragments: 12 coalesced 16B loads from the prepped table ----
    short8 bfrag[6][2];
    if (PREP) {
#pragma unroll
        for (int n = 0; n < 2; ++n)
#pragma unroll
            for (int s = 0; s < 6; ++s)
                bfrag[s][n] = wtab[(((wave * 2 + n) * 6 + s) << 6) + lane];
    } else {
        // fallback (workspace too small): build in-kernel
#pragma unroll
        for (int n = 0; n < 2; ++n) {
            const int f = (wave * 2 + n) * 16 + nl;
            const float* __restrict__ wf = w + f;
#pragma unroll
            for (int s = 0; s < 6; ++s) {
                float t[8];
#pragma unroll
                for (int j = 0; j < 8; ++j)
                    t[j] = wf[(s * 32 + q * 8 + j) * F_OUT];
                union { unsigned u[4]; short8 v; } hb;
                hb.u[0] = pk2(t[0], t[1]);
                hb.u[1] = pk2(t[2], t[3]);
                hb.u[2] = pk2(t[4], t[5]);
                hb.u[3] = pk2(t[6], t[7]);
                bfrag[s][n] = hb.v;
            }
        }
    }

    // bias: swapped C/D layout -> lane holds f = base + q*4 + r -> float4
    float4 bv[2];
#pragma unroll
    for (int n = 0; n < 2; ++n)
        bv[n] = *(const float4*)(bias + (wave * 2 + n) * 16 + q * 4);

    // ---- async DMA of one tile into LDS buffer `dbuf` (linear dest,
    //      XOR-swizzled source chunks). Exactly 5 VMEM issues per wave. ----
    auto stage = [&](float* dbuf, int l0) {
        // rows 0..63: 1024 chunks, 4 per thread, NO branch (uniform)
#pragma unroll
        for (int r = 0; r < 4; ++r) {
            int c   = r * 256 + tid;               // < 1024 always
            int row = c >> 4;
            int pc  = c & 15;
            int spc = pc ^ (row & 7);              // source chunk within row
            const float* src =
                x + ((size_t)(b * L_IN + l0 + row)) * C_INCH + spc * 4;
            float* dst = &dbuf[(r * 256 + wave * 64) * 4];  // wave-uniform base
            __builtin_amdgcn_global_load_lds(
                (const __attribute__((address_space(1))) void*)src,
                (__attribute__((address_space(3))) void*)dst, 16, 0, 0);
        }
        // halo rows 64..65: lanes 0..31 of EVERY wave (uniform vmcnt count);
        // 4 waves write identical bytes to the same LDS region (benign).
        {
            int row  = 64 + (lane >> 4);
            int pc   = lane & 15;
            int spc  = pc ^ (row & 7);
            int grow = b * L_IN + l0 + row;        // clamp: OOB rows only feed
            grow = grow < (B_SZ * L_IN - 1) ?      //        non-stored outputs
                   grow : (B_SZ * L_IN - 1);
            const float* src = x + (size_t)grow * C_INCH + spc * 4;
            float* dst = &dbuf[1024 * 4];          // row 64; HW adds lane*16
            if (lane < 32)
                __builtin_amdgcn_global_load_lds(
                    (const __attribute__((address_space(1))) void*)src,
                    (__attribute__((address_space(3))) void*)dst, 16, 0, 0);
        }
    };

    // ---- prologue: issue BOTH tiles' DMAs, wait only for tile 0 ----
    stage(a_raw[0], l_base);
    stage(a_raw[1], l_base + TILE_L);
    asm volatile("s_waitcnt vmcnt(5)" ::: "memory");  // buf0 landed; buf1 in flight
    __builtin_amdgcn_s_barrier();

#pragma unroll
    for (int t = 0; t < TPB; ++t) {
        const float* buf = a_raw[t];
        const int l0 = l_base + t * TILE_L;

        // ---- K-loop: 6 steps of 32; 4 m x 2 n per wave (swapped operands).
        //      A-fragment: 2 swizzled 16B chunks -> 2 ds_read_b128 + 4 cvt_pk.
        floatx4 acc[4][2];
#pragma unroll
        for (int m = 0; m < 4; ++m)
#pragma unroll
            for (int n = 0; n < 2; ++n) acc[m][n] = (floatx4){0.f, 0.f, 0.f, 0.f};

#pragma unroll
        for (int s = 0; s < 6; ++s) {
#pragma unroll
            for (int m = 0; m < 4; ++m) {
                const int row = m * 16 + nl + (s >> 1);
                const int fxr = row & 7;
                const int pc0 = (s & 1) * 8 + q * 2;   // even
                floatx4 c0 = *(const floatx4*)&buf[row * C_INCH + (pc0 ^ fxr) * 4];
                floatx4 c1 = *(const floatx4*)&buf[row * C_INCH + ((pc0 + 1) ^ fxr) * 4];
                union { unsigned u[4]; short8 v; } h;
                h.u[0] = pk2(c0[0], c0[1]);
                h.u[1] = pk2(c0[2], c0[3]);
                h.u[2] = pk2(c1[0], c1[1]);
                h.u[3] = pk2(c1[2], c1[3]);
#pragma unroll
                for (int n = 0; n < 2; ++n)
                    acc[m][n] = __builtin_amdgcn_mfma_f32_16x16x32_bf16(
                        bfrag[s][n], h.v, acc[m][n], 0, 0, 0);
            }
        }

        // ---- epilogue: lane(nl,q) holds f = base+q*4+r, l = l0+m*16+nl ----
#pragma unroll
        for (int n = 0; n < 2; ++n) {
            const int fb = (wave * 2 + n) * 16 + q * 4;
#pragma unroll
            for (int m = 0; m < 4; ++m) {
                const int l = l0 + m * 16 + nl;
                if (l < L_OUT) {
                    float4 v;
                    v.x = acc[m][n][0] + bv[n].x;
                    v.y = acc[m][n][1] + bv[n].y;
                    v.z = acc[m][n][2] + bv[n].z;
                    v.w = acc[m][n][3] + bv[n].w;
                    v.x = v.x > 0.f ? v.x : 0.f;
                    v.y = v.y > 0.f ? v.y : 0.f;
                    v.z = v.z > 0.f ? v.z : 0.f;
                    v.w = v.w > 0.f ? v.w : 0.f;
                    *(float4*)(out + ((size_t)b * L_OUT + l) * F_OUT + fb) = v;
                }
            }
        }

        // ---- tile boundary: wait for buf1's 5 DMAs (oldest); the 8 newest
        //      VMEM ops are our stores -> vmcnt(8). Never vmcnt(0) in-loop. ----
        if (t + 1 < TPB) {
            asm volatile("s_waitcnt vmcnt(8)" ::: "memory");
            __builtin_amdgcn_s_barrier();
        }
    }
}

extern "C" void kernel_launch(void* const* d_in, const int* in_sizes, int n_in,
                              void* d_out, int out_size, void* d_ws, size_t ws_size,
                              hipStream_t stream) {
    const float* x    = (const float*)d_in[0];
    const float* w    = (const float*)d_in[1];
    const float* bias = (const float*)d_in[2];
    float* out        = (float*)d_out;

    if (d_ws != nullptr && ws_size >= (size_t)WTAB_ELEMS * sizeof(short8)) {
        short8* wtab = (short8*)d_ws;
        w_prep<<<dim3((WTAB_ELEMS + 255) / 256), 256, 0, stream>>>(w, wtab);
        conv1d_mfma<true><<<dim3(NGRID), 256, 0, stream>>>(x, w, bias, out, wtab);
    } else {
        conv1d_mfma<false><<<dim3(NGRID), 256, 0, stream>>>(x, w, bias, out, nullptr);
    }
}